// Round 7
// baseline (27.435 us; speedup 1.0000x reference)
//
#include <hip/hip_runtime.h>
#include <hip/hip_bf16.h>

// Chamfer loss via MFMA, B=16, N=4096, D=3, fp32 in/out.
// d2[p][q] = ||p||^2 + ||q||^2 - 2 p.q as one 32x32x16 f16 MFMA per tile,
// hi/lo f16 split (error ~1e-3; ||q||^2 added per-column after the min).
// Single fused kernel: each block stages its 1024-row A-slice as MFMA
// fragments in LDS (32 KB), then sweeps 32 row-tiles x 4 B-frags (512 q-cols).
// A-tile read feeds 4 MFMAs -> LDS demand ~32 B/cyc/CU << 85 B/cyc ceiling.
// Directions/batches/row-splits combined by uint atomicMin on >=0 floats.

typedef _Float16 half8    __attribute__((ext_vector_type(8)));
typedef float    floatx16 __attribute__((ext_vector_type(16)));

#define CH_B 16
#define CH_N 4096
#define CH_BLOCK 256
#define CH_QT 512                          // q-cols per block (128/wave, 4 frags)
#define CH_NQT (CH_N / CH_QT)              // 8
#define CH_PSPLIT 4
#define CH_ROWS (CH_N / CH_PSPLIT)         // 1024 rows per block
#define CH_TILES (CH_ROWS / 32)            // 32 row-tiles per block
#define CH_NSLICE (2 * CH_B * CH_PSPLIT)   // 128 row-slices
#define CH_NBLK (CH_NSLICE * CH_NQT)       // 1024 blocks

__global__ __launch_bounds__(CH_BLOCK, 4) void chamfer_fused(
    const float* __restrict__ src, const float* __restrict__ trg,
    unsigned int* __restrict__ out_all)
{
    __shared__ half8 sp[CH_TILES * 64];   // 32 KB A-fragments

    const int tid  = threadIdx.x;
    const int lane = tid & 63;
    const int wave = tid >> 6;
    const int l31  = lane & 31;
    const int lhi  = lane >> 5;

    // Same-slice blocks share (L % 128) -> same (L % 8) -> same XCD (raw
    // point reads L2-hit). qt = L>>7 picks the q-tile.
    const int L     = blockIdx.x;     // 0..1023
    const int qt    = L >> 7;         // 0..7
    const int slice = L & 127;
    const int psl   = slice & 3;
    const int bz    = slice >> 2;     // dir*16 + b
    const int b     = bz & (CH_B - 1);
    const int dir   = bz >> 4;

    const float* P = dir ? trg : src;
    const float* Q = dir ? src : trg;
    const float* Pb = P + ((size_t)b * CH_N + (size_t)psl * CH_ROWS) * 3;
    const float* Qb = Q + (size_t)b * CH_N * 3;
    unsigned int* out = out_all + ((size_t)dir * CH_B + b) * CH_N;

    // ---- stage A-frags: 4 points/thread from 3 coalesced float4 loads ----
    // (Pb is 12288B-aligned: (b*4096+psl*1024)*3*4 is a multiple of 16.)
    {
        const float4* p4 = (const float4*)Pb;
        const float4 v0 = p4[tid * 3 + 0];
        const float4 v1 = p4[tid * 3 + 1];
        const float4 v2 = p4[tid * 3 + 2];
        const float px[4] = {v0.x, v0.w, v1.z, v2.y};
        const float py[4] = {v0.y, v1.x, v1.w, v2.z};
        const float pz[4] = {v0.z, v1.y, v2.x, v2.w};
        #pragma unroll
        for (int j = 0; j < 4; ++j) {
            const float ax = -2.0f * px[j], ay = -2.0f * py[j], az = -2.0f * pz[j];
            const float pn = px[j] * px[j] + py[j] * py[j] + pz[j] * pz[j];
            const _Float16 axh = (_Float16)ax, ayh = (_Float16)ay, azh = (_Float16)az;
            const _Float16 axl = (_Float16)(ax - (float)axh);
            const _Float16 ayl = (_Float16)(ay - (float)ayh);
            const _Float16 azl = (_Float16)(az - (float)azh);
            const _Float16 pnh = (_Float16)pn, pnl = (_Float16)(pn - (float)pnh);
            const _Float16 z0 = (_Float16)0.0f;
            const half8 k0 = {pnh, pnl, axh, ayh, azh, axl, ayl, azl};  // k 0..7
            const half8 k1 = {axh, ayh, azh, z0, z0, z0, z0, z0};       // k 8..15
            const int r = tid * 4 + j;
            sp[(r >> 5) * 64 + (r & 31)]      = k0;
            sp[(r >> 5) * 64 + 32 + (r & 31)] = k1;
        }
    }

    // ---- B fragments: 4 sets of 32 cols each (128 cols per wave) ----
    half8 bfrag[4];
    float qn[4], m[4];
    const int col0 = qt * CH_QT + wave * 128 + l31;
    #pragma unroll
    for (int s = 0; s < 4; ++s) {
        const int col = col0 + s * 32;
        const float qx = Qb[col * 3 + 0], qy = Qb[col * 3 + 1], qz = Qb[col * 3 + 2];
        qn[s] = qx * qx + qy * qy + qz * qz;
        m[s]  = __builtin_inff();
        const _Float16 xh = (_Float16)qx, yh = (_Float16)qy, zh = (_Float16)qz;
        const _Float16 xl = (_Float16)(qx - (float)xh);
        const _Float16 yl = (_Float16)(qy - (float)yh);
        const _Float16 zl = (_Float16)(qz - (float)zh);
        half8 f;
        if (lhi == 0) {      // k = 0..7
            f[0] = (_Float16)1.0f; f[1] = (_Float16)1.0f;
            f[2] = xh; f[3] = yh; f[4] = zh;
            f[5] = xh; f[6] = yh; f[7] = zh;
        } else {             // k = 8..15
            f[0] = xl; f[1] = yl; f[2] = zl;
            f[3] = (_Float16)0.0f; f[4] = (_Float16)0.0f;
            f[5] = (_Float16)0.0f; f[6] = (_Float16)0.0f; f[7] = (_Float16)0.0f;
        }
        bfrag[s] = f;
    }

    __syncthreads();

    const floatx16 zero = {0.f,0.f,0.f,0.f,0.f,0.f,0.f,0.f,
                           0.f,0.f,0.f,0.f,0.f,0.f,0.f,0.f};

    // ---- main loop: 1 ds_read_b128 -> 4 MFMAs -> 4 min3-reductions ----
    half8 a0 = sp[lane];
    #pragma unroll 1
    for (int t = 0; t < CH_TILES; ++t) {
        half8 a1 = a0;
        if (t + 1 < CH_TILES) a1 = sp[(t + 1) * 64 + lane];  // prefetch next
        #pragma unroll
        for (int s = 0; s < 4; ++s) {
            const floatx16 d =
                __builtin_amdgcn_mfma_f32_32x32x16_f16(a0, bfrag[s], zero, 0, 0, 0);
            const float u0 = fminf(fminf(d[0],  d[1]),  d[2]);
            const float u1 = fminf(fminf(d[3],  d[4]),  d[5]);
            const float u2 = fminf(fminf(d[6],  d[7]),  d[8]);
            const float u3 = fminf(fminf(d[9],  d[10]), d[11]);
            const float u4 = fminf(fminf(d[12], d[13]), d[14]);
            const float v  = fminf(fminf(u0, u1), u2);
            const float w  = fminf(fminf(u3, u4), d[15]);
            m[s] = fminf(fminf(m[s], v), w);
        }
        a0 = a1;
    }

    // ---- epilogue: add ||q||^2, clamp >=0, fold row-halves, atomicMin ----
    #pragma unroll
    for (int s = 0; s < 4; ++s) {
        float v = fmaxf(m[s] + qn[s], 0.0f);
        v = fminf(v, __shfl_xor(v, 32));
        if (lane < 32) atomicMin(&out[col0 + s * 32], __float_as_uint(v));
    }
}

extern "C" void kernel_launch(void* const* d_in, const int* in_sizes, int n_in,
                              void* d_out, int out_size, void* d_ws, size_t ws_size,
                              hipStream_t stream) {
    const float* src = (const float*)d_in[0];
    const float* trg = (const float*)d_in[1];
    unsigned int* out = (unsigned int*)d_out;

    // Init outputs to 0x7f7f7f7f (~3.4e38): valid +inf under uint-ordered min
    // for nonnegative values. (Graph-capture-safe; proven in round 2.)
    hipMemsetAsync(out, 0x7f, (size_t)2 * CH_B * CH_N * sizeof(float), stream);

    chamfer_fused<<<dim3(CH_NBLK), dim3(CH_BLOCK), 0, stream>>>(src, trg, out);
}

// Round 9
// 24.791 us; speedup vs baseline: 1.1066x; 1.1066x over previous
//
#include <hip/hip_runtime.h>

// Chamfer loss via MFMA, B=16, N=4096, D=3, fp32 in/out. Single dispatch.
// d2[p][q] = ||p||^2 + ||q||^2 - 2 p.q as one 32x32x16 f16 MFMA per tile,
// hi/lo f16 split (error ~1e-3; ||q||^2 added per-column after the min).
// Each block owns 256 output cols x ALL 4096 rows -> complete min -> plain
// stores (no atomics, no output init). Rows staged in 8 double-buffered
// 512-row LDS chunks; next chunk's global loads issue before compute, LDS
// writes land after (async-split). Wave phase-stagger decorrelates MFMA
// bursts after each barrier.

typedef _Float16 half8    __attribute__((ext_vector_type(8)));
typedef float    floatx16 __attribute__((ext_vector_type(16)));

#define CH_B 16
#define CH_N 4096
#define CH_BLOCK 256
#define CH_COLS 256                    // output cols per block (64/wave)
#define CH_NCT (CH_N / CH_COLS)        // 16 col-tiles per (dir,b)
#define CH_CHUNK 512                   // staged rows per chunk
#define CH_NCHUNK (CH_N / CH_CHUNK)    // 8
#define CH_CT (CH_CHUNK / 32)          // 16 row-tiles per chunk
#define CH_NBLK (2 * CH_B * CH_NCT)    // 512 blocks (2 per CU)

__global__ __launch_bounds__(CH_BLOCK, 2) void chamfer_one(
    const float* __restrict__ src, const float* __restrict__ trg,
    float* __restrict__ out_all)
{
    __shared__ half8 sp[2][CH_CT * 64];   // 2 x 16 KB A-fragment buffers

    const int tid  = threadIdx.x;
    const int lane = tid & 63;
    const int wave = tid >> 6;
    const int l31  = lane & 31;
    const int lhi  = lane >> 5;

    const int L   = blockIdx.x;        // 0..511
    const int ct  = L & (CH_NCT - 1);  // col-tile
    const int bz  = L >> 4;            // dir*16 + b
    const int b   = bz & (CH_B - 1);
    const int dir = bz >> 4;

    const float* P  = dir ? trg : src;
    const float* Q  = dir ? src : trg;
    const float* Pb = P + (size_t)b * CH_N * 3;
    const float* Qb = Q + (size_t)b * CH_N * 3;
    float* out = out_all + ((size_t)dir * CH_B + b) * CH_N;

    // ---- B fragments: 2 sets of 32 cols (64 cols per wave) ----
    half8 bfrag[2];
    float qn[2], m[2];
    const int col0 = ct * CH_COLS + wave * 64 + l31;
    #pragma unroll
    for (int s = 0; s < 2; ++s) {
        const int col = col0 + s * 32;
        const float qx = Qb[col * 3 + 0], qy = Qb[col * 3 + 1], qz = Qb[col * 3 + 2];
        qn[s] = qx * qx + qy * qy + qz * qz;
        m[s]  = __builtin_inff();
        const _Float16 xh = (_Float16)qx, yh = (_Float16)qy, zh = (_Float16)qz;
        const _Float16 xl = (_Float16)(qx - (float)xh);
        const _Float16 yl = (_Float16)(qy - (float)yh);
        const _Float16 zl = (_Float16)(qz - (float)zh);
        half8 f;
        if (lhi == 0) {      // k = 0..7
            f[0] = (_Float16)1.0f; f[1] = (_Float16)1.0f;
            f[2] = xh; f[3] = yh; f[4] = zh;
            f[5] = xh; f[6] = yh; f[7] = zh;
        } else {             // k = 8..15
            f[0] = xl; f[1] = yl; f[2] = zl;
            f[3] = (_Float16)0.0f; f[4] = (_Float16)0.0f;
            f[5] = (_Float16)0.0f; f[6] = (_Float16)0.0f; f[7] = (_Float16)0.0f;
        }
        bfrag[s] = f;
    }

    // ---- staging: 2 rows per thread per chunk (scalar loads, always safe) ----
    const int r0 = (tid >> 5) * 64 + (tid & 31);   // rows 0..511, (r&31)=tid&31
    const int r1 = r0 + 32;

    float pa[3], pb[3];
    auto loadpts = [&](int c) {
        const float* base = Pb + (size_t)c * CH_CHUNK * 3;
        pa[0] = base[r0 * 3 + 0];
        pa[1] = base[r0 * 3 + 1];
        pa[2] = base[r0 * 3 + 2];
        pb[0] = base[r1 * 3 + 0];
        pb[1] = base[r1 * 3 + 1];
        pb[2] = base[r1 * 3 + 2];
    };
    auto writept = [&](int buf, int r, float px, float py, float pz) {
        const float ax = -2.0f * px, ay = -2.0f * py, az = -2.0f * pz;
        const float pn = px * px + py * py + pz * pz;
        const _Float16 axh = (_Float16)ax, ayh = (_Float16)ay, azh = (_Float16)az;
        const _Float16 axl = (_Float16)(ax - (float)axh);
        const _Float16 ayl = (_Float16)(ay - (float)ayh);
        const _Float16 azl = (_Float16)(az - (float)azh);
        const _Float16 pnh = (_Float16)pn, pnl = (_Float16)(pn - (float)pnh);
        const _Float16 z0 = (_Float16)0.0f;
        const half8 k0 = {pnh, pnl, axh, ayh, azh, axl, ayl, azl};  // k 0..7
        const half8 k1 = {axh, ayh, azh, z0, z0, z0, z0, z0};       // k 8..15
        sp[buf][(r >> 5) * 64 + (r & 31)]      = k0;
        sp[buf][(r >> 5) * 64 + 32 + (r & 31)] = k1;
    };

    // prologue: stage chunk 0
    loadpts(0);
    writept(0, r0, pa[0], pa[1], pa[2]);
    writept(0, r1, pb[0], pb[1], pb[2]);
    __syncthreads();

    const floatx16 zero = {0.f,0.f,0.f,0.f,0.f,0.f,0.f,0.f,
                           0.f,0.f,0.f,0.f,0.f,0.f,0.f,0.f};
    const int off = wave * 4;   // per-wave tile-phase stagger

    #pragma unroll 1
    for (int c = 0; c < CH_NCHUNK; ++c) {
        const int cur = c & 1;
        const bool more = (c + 1 < CH_NCHUNK);
        if (more) loadpts(c + 1);   // issue early; consumed after compute

        const half8* buf = sp[cur];
        half8 a0 = buf[(off & 15) * 64 + lane];
        #pragma unroll 4
        for (int t = 0; t < CH_CT; ++t) {
            half8 a1 = a0;
            if (t + 1 < CH_CT) a1 = buf[((t + 1 + off) & 15) * 64 + lane];
            const floatx16 d0 =
                __builtin_amdgcn_mfma_f32_32x32x16_f16(a0, bfrag[0], zero, 0, 0, 0);
            const floatx16 d1 =
                __builtin_amdgcn_mfma_f32_32x32x16_f16(a0, bfrag[1], zero, 0, 0, 0);
            {
                const float u0 = fminf(fminf(d0[0],  d0[1]),  d0[2]);
                const float u1 = fminf(fminf(d0[3],  d0[4]),  d0[5]);
                const float u2 = fminf(fminf(d0[6],  d0[7]),  d0[8]);
                const float u3 = fminf(fminf(d0[9],  d0[10]), d0[11]);
                const float u4 = fminf(fminf(d0[12], d0[13]), d0[14]);
                const float v  = fminf(fminf(u0, u1), u2);
                const float w  = fminf(fminf(u3, u4), d0[15]);
                m[0] = fminf(fminf(m[0], v), w);
            }
            {
                const float u0 = fminf(fminf(d1[0],  d1[1]),  d1[2]);
                const float u1 = fminf(fminf(d1[3],  d1[4]),  d1[5]);
                const float u2 = fminf(fminf(d1[6],  d1[7]),  d1[8]);
                const float u3 = fminf(fminf(d1[9],  d1[10]), d1[11]);
                const float u4 = fminf(fminf(d1[12], d1[13]), d1[14]);
                const float v  = fminf(fminf(u0, u1), u2);
                const float w  = fminf(fminf(u3, u4), d1[15]);
                m[1] = fminf(fminf(m[1], v), w);
            }
            a0 = a1;
        }

        if (more) {   // LDS writes late: global-load latency hidden by compute
            writept(cur ^ 1, r0, pa[0], pa[1], pa[2]);
            writept(cur ^ 1, r1, pb[0], pb[1], pb[2]);
        }
        __syncthreads();
    }

    // ---- epilogue: add ||q||^2, clamp >=0, fold row-halves, plain store ----
    #pragma unroll
    for (int s = 0; s < 2; ++s) {
        float v = fmaxf(m[s] + qn[s], 0.0f);
        v = fminf(v, __shfl_xor(v, 32));
        if (lane < 32) out[col0 + s * 32] = v;
    }
}

extern "C" void kernel_launch(void* const* d_in, const int* in_sizes, int n_in,
                              void* d_out, int out_size, void* d_ws, size_t ws_size,
                              hipStream_t stream) {
    const float* src = (const float*)d_in[0];
    const float* trg = (const float*)d_in[1];
    float* out = (float*)d_out;

    chamfer_one<<<dim3(CH_NBLK), dim3(CH_BLOCK), 0, stream>>>(src, trg, out);
}